// Round 17
// baseline (458.970 us; speedup 1.0000x reference)
//
#include <hip/hip_runtime.h>
#include <math.h>

#define BATCH 2
#define CDIM 256
#define LLEN 4096
#define NH 8
#define HD 32
#define PER 522
#define NPROJ 2088
#define NPROJ_PAD 2112
#define NCHUNK 256
#define CLEN 16

typedef __attribute__((ext_vector_type(8))) short short8;
typedef __attribute__((ext_vector_type(4))) float f32x4;

static __device__ __forceinline__ ushort f2bf(float f) {
    unsigned u = __float_as_uint(f);
    u += 0x7fffu + ((u >> 16) & 1u);
    return (ushort)(u >> 16);
}
static __device__ __forceinline__ float bf2f(ushort u) {
    return __uint_as_float(((unsigned)u) << 16);
}

// ---------------- transpose-convert: W [K][N] f32 -> Wt [Npad][K] bf16 ----------------
__global__ __launch_bounds__(256) void convert_wt(
    const float* __restrict__ W, ushort* __restrict__ Wt, int K, int N)
{
    __shared__ float tile[32][33];
    int n0 = blockIdx.x * 32, k0 = blockIdx.y * 32;
    int t = threadIdx.x;
    int nl = t & 31, kl = t >> 5;
    #pragma unroll
    for (int i = 0; i < 4; i++) {
        int n = n0 + nl;
        tile[kl + i * 8][nl] = (n < N) ? W[(long)(k0 + kl + i * 8) * N + n] : 0.f;
    }
    __syncthreads();
    int kl2 = t & 31, nl2 = t >> 5;
    #pragma unroll
    for (int i = 0; i < 4; i++)
        Wt[(long)(n0 + nl2 + i * 8) * K + k0 + kl2] = f2bf(tile[kl2][nl2 + i * 8]);
}

// ---------------- transpose-convert x (B,256,L) f32 -> xbf (B,L,256) bf16 ----------------
__global__ __launch_bounds__(256) void convert_x(
    const float* __restrict__ x, ushort* __restrict__ xbf)
{
    __shared__ float tile[32][33];
    int l0 = blockIdx.x * 32, c0 = blockIdx.y * 32, b = blockIdx.z;
    int t = threadIdx.x;
    int ll = t & 31, cl = t >> 5;
    #pragma unroll
    for (int i = 0; i < 4; i++)
        tile[cl + i * 8][ll] = x[((long)b * CDIM + c0 + cl + i * 8) * LLEN + l0 + ll];
    __syncthreads();
    int cl2 = t & 31, ll2 = t >> 5;
    #pragma unroll
    for (int i = 0; i < 4; i++)
        xbf[((long)b * LLEN + l0 + ll2 + i * 8) * CDIM + c0 + cl2] = f2bf(tile[cl2][ll2 + i * 8]);
}

// ---------------- convert conv weights -> bf16 [d][tap][co][ci] ----------------
__global__ __launch_bounds__(256) void convert_w(
    const float* __restrict__ cw, ushort* __restrict__ wbf)
{
    __shared__ ushort tmp[4608];
    int blk = blockIdx.x;        // d*512 + co
    int t = threadIdx.x;
    const float* src = cw + (long)blk * 4608;
    for (int q = t; q < 4608; q += 256) tmp[q] = f2bf(src[q]);
    __syncthreads();
    int d = blk >> 9, co = blk & 511;
    for (int q = t; q < 4608; q += 256) {
        int tt = q >> 9, ci = q & 511;
        wbf[(((long)(d * 9 + tt) * 512 + co) << 9) + ci] = tmp[ci * 9 + tt];
    }
}

// ---------------- in-proj GEMM with fused scatter epilogue ----------------
__global__ __launch_bounds__(256) void gemm_in(
    const ushort* __restrict__ A, const ushort* __restrict__ Bt,
    ushort* __restrict__ cinb, float* __restrict__ bcdt)
{
    __shared__ ushort As[128][72];
    __shared__ ushort Bs[64][72];
    const int K = CDIM;
    int m0 = blockIdx.x * 128, n0 = blockIdx.y * 64;
    int t = threadIdx.x;
    int wave = t >> 6, lane = t & 63;
    int l15 = lane & 15, ko = lane >> 4;
    int mbase = wave * 32;

    f32x4 acc[2][4];
    #pragma unroll
    for (int mt = 0; mt < 2; mt++)
        #pragma unroll
        for (int nt = 0; nt < 4; nt++) acc[mt][nt] = (f32x4){0.f, 0.f, 0.f, 0.f};

    for (int k0 = 0; k0 < K; k0 += 64) {
        #pragma unroll
        for (int i = 0; i < 4; i++) {
            int g = t + 256 * i;
            int row = g >> 3, grp = g & 7;
            *(uint4*)&As[row][grp * 8] = *(const uint4*)&A[(long)(m0 + row) * K + k0 + grp * 8];
        }
        #pragma unroll
        for (int i = 0; i < 2; i++) {
            int g = t + 256 * i;
            int row = g >> 3, grp = g & 7;
            *(uint4*)&Bs[row][grp * 8] = *(const uint4*)&Bt[(long)(n0 + row) * K + k0 + grp * 8];
        }
        __syncthreads();
        #pragma unroll
        for (int kk = 0; kk < 2; kk++) {
            short8 a0 = *(const short8*)&As[mbase + l15][kk * 32 + ko * 8];
            short8 a1 = *(const short8*)&As[mbase + 16 + l15][kk * 32 + ko * 8];
            short8 bb[4];
            #pragma unroll
            for (int nt = 0; nt < 4; nt++)
                bb[nt] = *(const short8*)&Bs[nt * 16 + l15][kk * 32 + ko * 8];
            #pragma unroll
            for (int nt = 0; nt < 4; nt++) {
                acc[0][nt] = __builtin_amdgcn_mfma_f32_16x16x32_bf16(a0, bb[nt], acc[0][nt], 0, 0, 0);
                acc[1][nt] = __builtin_amdgcn_mfma_f32_16x16x32_bf16(a1, bb[nt], acc[1][nt], 0, 0, 0);
            }
        }
        __syncthreads();
    }
    #pragma unroll
    for (int nt = 0; nt < 4; nt++) {
        int n = n0 + nt * 16 + l15;
        if (n < NPROJ) {
            int d = n / PER;
            int r = n - d * PER;
            #pragma unroll
            for (int mt = 0; mt < 2; mt++)
                #pragma unroll
                for (int reg = 0; reg < 4; reg++) {
                    int m = m0 + mbase + mt * 16 + ko * 4 + reg;
                    int b = m >> 12, l = m & (LLEN - 1);
                    float v = acc[mt][nt][reg];
                    if (r < 512) {
                        int ch = (r < 256) ? (256 + r) : (r - 256);
                        cinb[(((long)d * BATCH + b) * LLEN + l) * 512 + ch] = f2bf(v);
                    } else {
                        bcdt[(long)m * 48 + d * 12 + (r - 512)] = v;
                    }
                }
        }
    }
}

// ---------------- generic bf16 MFMA GEMM (out-proj) ----------------
__global__ __launch_bounds__(256) void gemm_bt(
    const ushort* __restrict__ A, const ushort* __restrict__ Bt, float* __restrict__ C,
    int K, int N)
{
    __shared__ ushort As[128][72];
    __shared__ ushort Bs[64][72];
    int m0 = blockIdx.x * 128, n0 = blockIdx.y * 64;
    int t = threadIdx.x;
    int wave = t >> 6, lane = t & 63;
    int l15 = lane & 15, ko = lane >> 4;
    int mbase = wave * 32;

    f32x4 acc[2][4];
    #pragma unroll
    for (int mt = 0; mt < 2; mt++)
        #pragma unroll
        for (int nt = 0; nt < 4; nt++) acc[mt][nt] = (f32x4){0.f, 0.f, 0.f, 0.f};

    for (int k0 = 0; k0 < K; k0 += 64) {
        #pragma unroll
        for (int i = 0; i < 4; i++) {
            int g = t + 256 * i;
            int row = g >> 3, grp = g & 7;
            *(uint4*)&As[row][grp * 8] = *(const uint4*)&A[(long)(m0 + row) * K + k0 + grp * 8];
        }
        #pragma unroll
        for (int i = 0; i < 2; i++) {
            int g = t + 256 * i;
            int row = g >> 3, grp = g & 7;
            *(uint4*)&Bs[row][grp * 8] = *(const uint4*)&Bt[(long)(n0 + row) * K + k0 + grp * 8];
        }
        __syncthreads();
        #pragma unroll
        for (int kk = 0; kk < 2; kk++) {
            short8 a0 = *(const short8*)&As[mbase + l15][kk * 32 + ko * 8];
            short8 a1 = *(const short8*)&As[mbase + 16 + l15][kk * 32 + ko * 8];
            short8 bb[4];
            #pragma unroll
            for (int nt = 0; nt < 4; nt++)
                bb[nt] = *(const short8*)&Bs[nt * 16 + l15][kk * 32 + ko * 8];
            #pragma unroll
            for (int nt = 0; nt < 4; nt++) {
                acc[0][nt] = __builtin_amdgcn_mfma_f32_16x16x32_bf16(a0, bb[nt], acc[0][nt], 0, 0, 0);
                acc[1][nt] = __builtin_amdgcn_mfma_f32_16x16x32_bf16(a1, bb[nt], acc[1][nt], 0, 0, 0);
            }
        }
        __syncthreads();
    }
    #pragma unroll
    for (int nt = 0; nt < 4; nt++) {
        int n = n0 + nt * 16 + l15;
        if (n < N) {
            #pragma unroll
            for (int mt = 0; mt < 2; mt++)
                #pragma unroll
                for (int reg = 0; reg < 4; reg++) {
                    int m = m0 + mbase + mt * 16 + ko * 4 + reg;
                    C[(long)m * N + n] = acc[mt][nt][reg];
                }
        }
    }
}

// ---------------- conv3x3 512->512 via MFMA + gelu + bn, bf16 out, all dirs ----------------
// FROZEN at round-11 form (best measured: 308us, VGPR 64, Occ 46%). Do not touch.
// Structural ceiling: 64V+64A = 128 regs/wave -> hard 16 waves/CU; weights-from-global
// + LDS im2col leaves ~60% of cycles as latency gaps; every pipelining attempt
// (r9 DMA-dbuf, r10 T14, r12 rotation, r13 decode) regressed via regs/VALU.
__global__ __launch_bounds__(256, 2) void conv_mfma(
    const ushort* __restrict__ cinb, const ushort* __restrict__ wbf,
    const float* __restrict__ bn_g, const float* __restrict__ bn_b,
    const float* __restrict__ bn_m, const float* __restrict__ bn_v,
    ushort* __restrict__ convb)
{
    __shared__ ushort in_s[6][4][66][8];   // rows h0-1..h0+4, ko(4x8ci), px -1..64

    // XCD swizzle: slice = (d, co-tile) weight group; 4 slices per XCD
    int fid = blockIdx.x;
    int xcd = fid & 7;
    int k = fid >> 3;
    int slice = xcd * 4 + (k >> 5);
    int within = k & 31;
    int d = slice >> 3;
    int co0 = (slice & 7) * 64;
    int h0 = (within & 15) * 4;
    int b = within >> 4;
    int z = d * 2 + b;

    int t = threadIdx.x;
    int wave = t >> 6, lane = t & 63;
    int l15 = lane & 15, ko = lane >> 4;

    const ushort* conv_in = cinb + (long)z * LLEN * 512;
    ushort* conv_out = convb + (long)z * LLEN * 512;

    f32x4 acc[4][4];
    #pragma unroll
    for (int m = 0; m < 4; m++)
        #pragma unroll
        for (int nt = 0; nt < 4; nt++) acc[m][nt] = (f32x4){0.f, 0.f, 0.f, 0.f};

    // per-thread weight base: [d][tap][co0 + nt*16 + l15][ci0 + ko*8]
    const ushort* wtb = wbf + (long)d * 9 * 512 * 512 + (long)(co0 + l15) * 512 + ko * 8;

    for (int ci0 = 0; ci0 < 512; ci0 += 32) {
        // stage input: 6 rows x 66 px x 4 octs = 1584 x 16B (shift-only decode)
        for (int q = t; q < 1584; q += 256) {
            int oct = q & 3, pxg = q >> 2;
            int row = pxg / 66, px = pxg - row * 66;
            int hh = h0 + row - 1, wp = px - 1;
            uint4 val = make_uint4(0u, 0u, 0u, 0u);
            if (hh >= 0 && hh < 64 && wp >= 0 && wp < 64)
                val = *(const uint4*)&conv_in[(((long)hh) * 64 + wp) * 512 + ci0 + oct * 8];
            *(uint4*)&in_s[row][oct][px][0] = val;
        }
        // prefetch tap-0 weights
        const ushort* wp0 = wtb + ci0;
        short8 bw[4], bwn[4];
        #pragma unroll
        for (int nt = 0; nt < 4; nt++)
            bw[nt] = *(const short8*)&wp0[(long)nt * (16 * 512)];
        __syncthreads();
        #pragma unroll 1
        for (int tap = 0; tap < 9; tap++) {
            if (tap < 8) {
                const ushort* wq = wp0 + (long)(tap + 1) * (512 * 512);
                #pragma unroll
                for (int nt = 0; nt < 4; nt++)
                    bwn[nt] = *(const short8*)&wq[(long)nt * (16 * 512)];
            }
            int kh = (tap >= 6) ? 2 : ((tap >= 3) ? 1 : 0);
            int kw = tap - kh * 3;
            short8 av[4];
            #pragma unroll
            for (int m = 0; m < 4; m++)
                av[m] = *(const short8*)&in_s[wave + kh][ko][m * 16 + l15 + kw][0];
            #pragma unroll
            for (int m = 0; m < 4; m++)
                #pragma unroll
                for (int nt = 0; nt < 4; nt++)
                    acc[m][nt] = __builtin_amdgcn_mfma_f32_16x16x32_bf16(av[m], bw[nt], acc[m][nt], 0, 0, 0);
            #pragma unroll
            for (int nt = 0; nt < 4; nt++) bw[nt] = bwn[nt];
        }
        __syncthreads();
    }

    // epilogue: gelu(tanh approx via fast exp) + BN, write bf16 (B,L,512)
    int hgl = h0 + wave;
    #pragma unroll
    for (int nt = 0; nt < 4; nt++) {
        int co = co0 + nt * 16 + l15;
        float mean = bn_m[d * 512 + co], var = bn_v[d * 512 + co];
        float g = bn_g[d * 512 + co], bbias = bn_b[d * 512 + co];
        float inv = rsqrtf(var + 1e-3f);
        #pragma unroll
        for (int m = 0; m < 4; m++)
            #pragma unroll
            for (int reg = 0; reg < 4; reg++) {
                int wc = m * 16 + ko * 4 + reg;
                float v = acc[m][nt][reg];
                float u = -1.5957691216057308f * (v + 0.044715f * v * v * v);
                v = v / (1.f + __expf(u));
                v = (v - mean) * inv * g + bbias;
                conv_out[((long)hgl * 64 + wc) * 512 + co] = f2bf(v);
            }
    }
}

// ---------------- scan phase 1: per-chunk (Aprod, hfin), all 4 dirs ----------------
// 256 chunks x 16 steps: 2048 blocks (8/CU, fully resident) for max TLP.
__global__ __launch_bounds__(256) void scan_chunk(
    const float* __restrict__ bcdt, const ushort* __restrict__ conv_out,
    const int* __restrict__ mortonH, const int* __restrict__ mortonV,
    const float* __restrict__ fcos, const float* __restrict__ fsin,
    const float* __restrict__ dt_bias, const float* __restrict__ A_log,
    float* __restrict__ hfin, float* __restrict__ aprod_out)
{
    int chunk = blockIdx.x, b = blockIdx.y, d = blockIdx.z;
    const int* idx = (d < 2) ? mortonH : mortonV;
    int flip = d & 1;
    int c = threadIdx.x;
    int hh = c >> 5, p = c & 31;
    int i = p >> 1;
    float Acoef = -__expf(A_log[d * 8 + hh]);
    float dtb = dt_bias[d * 8 + hh];
    float hstate = 0.f, aprod = 1.f;
    const ushort* cop = conv_out + (long)(d * BATCH + b) * LLEN * 512;
    for (int jj = 0; jj < CLEN; jj++) {
        int j = chunk * CLEN + jj;
        int jsrc = flip ? (LLEN - 1 - j) : j;
        int src = idx[jsrc];
        const float* bc = bcdt + ((long)b * LLEN + src) * 48 + d * 12;
        float dtraw = bc[2 + hh] + dtb;
        float dtv = (dtraw > 20.f) ? dtraw : __logf(1.f + __expf(dtraw));
        float a = __expf(dtv * Acoef);
        float Bd = bc[0];
        const ushort* xrow = cop + (long)src * 512;
        uint xz = *(const uint*)&xrow[hh * 32 + (p & ~1)];
        float xe = bf2f((ushort)(xz & 0xffff));
        float xo = bf2f((ushort)(xz >> 16));
        float cs = fcos[j * 16 + i], sn = fsin[j * 16 + i];
        float xh = (p & 1) ? (xe * sn + xo * cs) : (xe * cs - xo * sn);
        hstate = a * hstate + dtv * xh * Bd;
        aprod *= a;
    }
    long o = (((long)(d * BATCH + b)) * NCHUNK + chunk) * 256 + c;
    hfin[o] = hstate;
    aprod_out[o] = aprod;
}

// ---------------- scan phase 2+3 fused: prefix fold + recompute + y + scatter ----------------
__global__ __launch_bounds__(256) void scan_final(
    const float* __restrict__ bcdt, const ushort* __restrict__ conv_out,
    const int* __restrict__ mortonH, const int* __restrict__ mortonV,
    const float* __restrict__ fcos, const float* __restrict__ fsin,
    const float* __restrict__ dt_bias, const float* __restrict__ A_log, const float* __restrict__ Dp,
    const float* __restrict__ hfin, const float* __restrict__ aprod, ushort* __restrict__ ycat)
{
    int chunk = blockIdx.x, b = blockIdx.y, d = blockIdx.z;
    const int* idx = (d < 2) ? mortonH : mortonV;
    int flip = d & 1;
    int c = threadIdx.x;
    int hh = c >> 5, p = c & 31;
    int i = p >> 1;
    float Acoef = -__expf(A_log[d * 8 + hh]);
    float dtb = dt_bias[d * 8 + hh];
    float Dv = Dp[d * 8 + hh];
    // prefix fold over preceding chunks
    float hstate = 0.f;
    {
        long ob = ((long)(d * BATCH + b)) * NCHUNK;
        for (int ch = 0; ch < chunk; ch++) {
            long o = (ob + ch) * 256 + c;
            hstate = aprod[o] * hstate + hfin[o];
        }
    }
    const ushort* cop = conv_out + (long)(d * BATCH + b) * LLEN * 512;
    for (int jj = 0; jj < CLEN; jj++) {
        int j = chunk * CLEN + jj;
        int jsrc = flip ? (LLEN - 1 - j) : j;
        int src = idx[jsrc];
        const float* bc = bcdt + ((long)b * LLEN + src) * 48 + d * 12;
        float dtraw = bc[2 + hh] + dtb;
        float dtv = (dtraw > 20.f) ? dtraw : __logf(1.f + __expf(dtraw));
        float a = __expf(dtv * Acoef);
        float Bd = bc[0];
        float Cd = bc[1];
        const ushort* xrow = cop + (long)src * 512;
        uint xz = *(const uint*)&xrow[hh * 32 + (p & ~1)];
        float xe = bf2f((ushort)(xz & 0xffff));
        float xo = bf2f((ushort)(xz >> 16));
        float cs = fcos[j * 16 + i], sn = fsin[j * 16 + i];
        float xh = (p & 1) ? (xe * sn + xo * cs) : (xe * cs - xo * sn);
        hstate = a * hstate + dtv * xh * Bd;
        float y = hstate * Cd + Dv * xh;
        float zd = bf2f(xrow[256 + c]);
        y *= zd / (1.f + __expf(-zd));         // y * silu(zd)
        ycat[((long)b * LLEN + src) * 1024 + d * 256 + c] = f2bf(y);
    }
}

// ---------------- layernorm + transpose to (B,C,H,W), wave-per-row ----------------
__global__ __launch_bounds__(256) void ln_out(
    const float* __restrict__ pre, const float* __restrict__ g, const float* __restrict__ bta,
    float* __restrict__ out)
{
    int wave = threadIdx.x >> 6, lane = threadIdx.x & 63;
    int row = blockIdx.x * 4 + wave;   // b*L + l
    float4 v = *(const float4*)&pre[(long)row * 256 + lane * 4];
    float s = v.x + v.y + v.z + v.w;
    float s2 = v.x * v.x + v.y * v.y + v.z * v.z + v.w * v.w;
    #pragma unroll
    for (int o = 32; o > 0; o >>= 1) {
        s += __shfl_down(s, o);
        s2 += __shfl_down(s2, o);
    }
    s = __shfl(s, 0);
    s2 = __shfl(s2, 0);
    float mean = s * (1.f / 256.f);
    float inv = rsqrtf(s2 * (1.f / 256.f) - mean * mean + 1e-6f);
    float4 gg = *(const float4*)&g[lane * 4];
    float4 bb = *(const float4*)&bta[lane * 4];
    int b = row >> 12, l = row & (LLEN - 1);
    float* ob = out + ((long)b * 256 + lane * 4) * (long)LLEN + l;
    ob[0]            = (v.x - mean) * inv * gg.x + bb.x;
    ob[LLEN]         = (v.y - mean) * inv * gg.y + bb.y;
    ob[2 * LLEN]     = (v.z - mean) * inv * gg.z + bb.z;
    ob[3 * LLEN]     = (v.w - mean) * inv * gg.w + bb.w;
}

extern "C" void kernel_launch(void* const* d_in, const int* in_sizes, int n_in,
                              void* d_out, int out_size, void* d_ws, size_t ws_size,
                              hipStream_t stream)
{
    const float* x        = (const float*)d_in[0];
    const float* fcos     = (const float*)d_in[1];
    const float* fsin     = (const float*)d_in[2];
    const int*   mortonH  = (const int*)d_in[3];
    const int*   mortonV  = (const int*)d_in[4];
    const float* W_in     = (const float*)d_in[7];
    const float* conv_w   = (const float*)d_in[8];
    const float* bn_g     = (const float*)d_in[9];
    const float* bn_b     = (const float*)d_in[10];
    const float* bn_m     = (const float*)d_in[11];
    const float* bn_v     = (const float*)d_in[12];
    const float* dt_bias  = (const float*)d_in[13];
    const float* A_log    = (const float*)d_in[14];
    const float* Dp       = (const float*)d_in[15];
    const float* W_out    = (const float*)d_in[16];
    const float* ln_g     = (const float*)d_in[17];
    const float* ln_b     = (const float*)d_in[18];
    float* out = (float*)d_out;

    float* ws = (float*)d_ws;
    // float-unit offsets
    const long CONVB_OFF   = 0;                                          // bf16 [4][2][4096][512] -> 8388608 slots
    const long HFIN_OFF    = CONVB_OFF + 8388608;                        // [4][2][256][256] f32
    const long APROD_OFF   = HFIN_OFF + 4L * BATCH * NCHUNK * 256;
    const long BCDT_OFF    = APROD_OFF + 4L * BATCH * NCHUNK * 256;      // (2*4096,48) f32
    const long WBF_OFF     = BCDT_OFF + (long)BATCH * LLEN * 48;         // bf16 4*9*512*512 -> 4718592 slots
    const long CINB_OFF    = WBF_OFF + 4718592;                          // bf16 4*2*4096*512 -> 8388608 slots
    const long XBF_OFF     = CINB_OFF + 8388608;                         // bf16 2*4096*256 -> 1048576 slots
    const long WINT_OFF    = XBF_OFF + 1048576;                          // bf16 2112*256 -> 270336 slots
    const long WOUTT_OFF   = WINT_OFF + 270336;                          // bf16 256*1024 -> 131072 slots
    const long YCATB_OFF   = WOUTT_OFF + 131072;                         // bf16 2*4096*1024 -> 4194304 slots
    const long PRE_OFF     = YCATB_OFF + 4194304;                        // (2,4096,256) f32

    ushort* convb   = (ushort*)(ws + CONVB_OFF);
    float* hfin     = ws + HFIN_OFF;
    float* aprod    = ws + APROD_OFF;
    float* bcdt     = ws + BCDT_OFF;
    ushort* wbf     = (ushort*)(ws + WBF_OFF);
    ushort* cinb    = (ushort*)(ws + CINB_OFF);
    ushort* xbf     = (ushort*)(ws + XBF_OFF);
    ushort* wint    = (ushort*)(ws + WINT_OFF);
    ushort* woutt   = (ushort*)(ws + WOUTT_OFF);
    ushort* ycatb   = (ushort*)(ws + YCATB_OFF);
    float* pre      = ws + PRE_OFF;

    // 0) one-time converts
    convert_w<<<4 * 512, 256, 0, stream>>>(conv_w, wbf);
    convert_wt<<<dim3(NPROJ_PAD / 32, CDIM / 32), 256, 0, stream>>>(W_in, wint, CDIM, NPROJ);
    convert_wt<<<dim3(CDIM / 32, 1024 / 32), 256, 0, stream>>>(W_out, woutt, 1024, CDIM);
    convert_x<<<dim3(LLEN / 32, CDIM / 32, BATCH), 256, 0, stream>>>(x, xbf);

    // 1) in-proj GEMM fused with direction scatter: M=8192, N=2088(pad 2112), K=256
    gemm_in<<<dim3(64, NPROJ_PAD / 64), 256, 0, stream>>>(xbf, wint, cinb, bcdt);

    // 2) conv (all directions, one dispatch): 1-D grid 1024 with XCD swizzle
    conv_mfma<<<1024, 256, 0, stream>>>(
        cinb, wbf, bn_g, bn_b, bn_m, bn_v, convb);

    // 3) scans (all directions merged; 256 chunks x 16 steps)
    scan_chunk<<<dim3(NCHUNK, BATCH, 4), 256, 0, stream>>>(
        bcdt, convb, mortonH, mortonV, fcos, fsin, dt_bias, A_log, hfin, aprod);
    scan_final<<<dim3(NCHUNK, BATCH, 4), 256, 0, stream>>>(
        bcdt, convb, mortonH, mortonV, fcos, fsin, dt_bias, A_log, Dp, hfin, aprod, ycatb);

    // 4) out GEMM: M=8192, N=256, K=1024
    gemm_bt<<<dim3(64, CDIM / 64), 256, 0, stream>>>(ycatb, woutt, pre, 1024, CDIM);

    // 5) LN + transpose (wave-per-row, no barriers)
    ln_out<<<BATCH * LLEN / 4, 256, 0, stream>>>(pre, ln_g, ln_b, out);
}

// Round 18
// 419.937 us; speedup vs baseline: 1.0930x; 1.0930x over previous
//
#include <hip/hip_runtime.h>
#include <math.h>

#define BATCH 2
#define CDIM 256
#define LLEN 4096
#define NH 8
#define HD 32
#define PER 522
#define NPROJ 2088
#define NPROJ_PAD 2112
#define NCHUNK 128
#define CLEN 32

typedef __attribute__((ext_vector_type(8))) short short8;
typedef __attribute__((ext_vector_type(4))) float f32x4;

static __device__ __forceinline__ ushort f2bf(float f) {
    unsigned u = __float_as_uint(f);
    u += 0x7fffu + ((u >> 16) & 1u);
    return (ushort)(u >> 16);
}
static __device__ __forceinline__ float bf2f(ushort u) {
    return __uint_as_float(((unsigned)u) << 16);
}

// ---------------- transpose-convert: W [K][N] f32 -> Wt [Npad][K] bf16 ----------------
__global__ __launch_bounds__(256) void convert_wt(
    const float* __restrict__ W, ushort* __restrict__ Wt, int K, int N)
{
    __shared__ float tile[32][33];
    int n0 = blockIdx.x * 32, k0 = blockIdx.y * 32;
    int t = threadIdx.x;
    int nl = t & 31, kl = t >> 5;
    #pragma unroll
    for (int i = 0; i < 4; i++) {
        int n = n0 + nl;
        tile[kl + i * 8][nl] = (n < N) ? W[(long)(k0 + kl + i * 8) * N + n] : 0.f;
    }
    __syncthreads();
    int kl2 = t & 31, nl2 = t >> 5;
    #pragma unroll
    for (int i = 0; i < 4; i++)
        Wt[(long)(n0 + nl2 + i * 8) * K + k0 + kl2] = f2bf(tile[kl2][nl2 + i * 8]);
}

// ---------------- transpose-convert x (B,256,L) f32 -> xbf (B,L,256) bf16 ----------------
__global__ __launch_bounds__(256) void convert_x(
    const float* __restrict__ x, ushort* __restrict__ xbf)
{
    __shared__ float tile[32][33];
    int l0 = blockIdx.x * 32, c0 = blockIdx.y * 32, b = blockIdx.z;
    int t = threadIdx.x;
    int ll = t & 31, cl = t >> 5;
    #pragma unroll
    for (int i = 0; i < 4; i++)
        tile[cl + i * 8][ll] = x[((long)b * CDIM + c0 + cl + i * 8) * LLEN + l0 + ll];
    __syncthreads();
    int cl2 = t & 31, ll2 = t >> 5;
    #pragma unroll
    for (int i = 0; i < 4; i++)
        xbf[((long)b * LLEN + l0 + ll2 + i * 8) * CDIM + c0 + cl2] = f2bf(tile[cl2][ll2 + i * 8]);
}

// ---------------- convert conv weights -> bf16 [d][tap][co][ci] ----------------
__global__ __launch_bounds__(256) void convert_w(
    const float* __restrict__ cw, ushort* __restrict__ wbf)
{
    __shared__ ushort tmp[4608];
    int blk = blockIdx.x;        // d*512 + co
    int t = threadIdx.x;
    const float* src = cw + (long)blk * 4608;
    for (int q = t; q < 4608; q += 256) tmp[q] = f2bf(src[q]);
    __syncthreads();
    int d = blk >> 9, co = blk & 511;
    for (int q = t; q < 4608; q += 256) {
        int tt = q >> 9, ci = q & 511;
        wbf[(((long)(d * 9 + tt) * 512 + co) << 9) + ci] = tmp[ci * 9 + tt];
    }
}

// ---------------- in-proj GEMM with fused scatter epilogue ----------------
__global__ __launch_bounds__(256) void gemm_in(
    const ushort* __restrict__ A, const ushort* __restrict__ Bt,
    ushort* __restrict__ cinb, float* __restrict__ bcdt)
{
    __shared__ ushort As[128][72];
    __shared__ ushort Bs[64][72];
    const int K = CDIM;
    int m0 = blockIdx.x * 128, n0 = blockIdx.y * 64;
    int t = threadIdx.x;
    int wave = t >> 6, lane = t & 63;
    int l15 = lane & 15, ko = lane >> 4;
    int mbase = wave * 32;

    f32x4 acc[2][4];
    #pragma unroll
    for (int mt = 0; mt < 2; mt++)
        #pragma unroll
        for (int nt = 0; nt < 4; nt++) acc[mt][nt] = (f32x4){0.f, 0.f, 0.f, 0.f};

    for (int k0 = 0; k0 < K; k0 += 64) {
        #pragma unroll
        for (int i = 0; i < 4; i++) {
            int g = t + 256 * i;
            int row = g >> 3, grp = g & 7;
            *(uint4*)&As[row][grp * 8] = *(const uint4*)&A[(long)(m0 + row) * K + k0 + grp * 8];
        }
        #pragma unroll
        for (int i = 0; i < 2; i++) {
            int g = t + 256 * i;
            int row = g >> 3, grp = g & 7;
            *(uint4*)&Bs[row][grp * 8] = *(const uint4*)&Bt[(long)(n0 + row) * K + k0 + grp * 8];
        }
        __syncthreads();
        #pragma unroll
        for (int kk = 0; kk < 2; kk++) {
            short8 a0 = *(const short8*)&As[mbase + l15][kk * 32 + ko * 8];
            short8 a1 = *(const short8*)&As[mbase + 16 + l15][kk * 32 + ko * 8];
            short8 bb[4];
            #pragma unroll
            for (int nt = 0; nt < 4; nt++)
                bb[nt] = *(const short8*)&Bs[nt * 16 + l15][kk * 32 + ko * 8];
            #pragma unroll
            for (int nt = 0; nt < 4; nt++) {
                acc[0][nt] = __builtin_amdgcn_mfma_f32_16x16x32_bf16(a0, bb[nt], acc[0][nt], 0, 0, 0);
                acc[1][nt] = __builtin_amdgcn_mfma_f32_16x16x32_bf16(a1, bb[nt], acc[1][nt], 0, 0, 0);
            }
        }
        __syncthreads();
    }
    #pragma unroll
    for (int nt = 0; nt < 4; nt++) {
        int n = n0 + nt * 16 + l15;
        if (n < NPROJ) {
            int d = n / PER;
            int r = n - d * PER;
            #pragma unroll
            for (int mt = 0; mt < 2; mt++)
                #pragma unroll
                for (int reg = 0; reg < 4; reg++) {
                    int m = m0 + mbase + mt * 16 + ko * 4 + reg;
                    int b = m >> 12, l = m & (LLEN - 1);
                    float v = acc[mt][nt][reg];
                    if (r < 512) {
                        int ch = (r < 256) ? (256 + r) : (r - 256);
                        cinb[(((long)d * BATCH + b) * LLEN + l) * 512 + ch] = f2bf(v);
                    } else {
                        bcdt[(long)m * 48 + d * 12 + (r - 512)] = v;
                    }
                }
        }
    }
}

// ---------------- generic bf16 MFMA GEMM (out-proj) ----------------
__global__ __launch_bounds__(256) void gemm_bt(
    const ushort* __restrict__ A, const ushort* __restrict__ Bt, float* __restrict__ C,
    int K, int N)
{
    __shared__ ushort As[128][72];
    __shared__ ushort Bs[64][72];
    int m0 = blockIdx.x * 128, n0 = blockIdx.y * 64;
    int t = threadIdx.x;
    int wave = t >> 6, lane = t & 63;
    int l15 = lane & 15, ko = lane >> 4;
    int mbase = wave * 32;

    f32x4 acc[2][4];
    #pragma unroll
    for (int mt = 0; mt < 2; mt++)
        #pragma unroll
        for (int nt = 0; nt < 4; nt++) acc[mt][nt] = (f32x4){0.f, 0.f, 0.f, 0.f};

    for (int k0 = 0; k0 < K; k0 += 64) {
        #pragma unroll
        for (int i = 0; i < 4; i++) {
            int g = t + 256 * i;
            int row = g >> 3, grp = g & 7;
            *(uint4*)&As[row][grp * 8] = *(const uint4*)&A[(long)(m0 + row) * K + k0 + grp * 8];
        }
        #pragma unroll
        for (int i = 0; i < 2; i++) {
            int g = t + 256 * i;
            int row = g >> 3, grp = g & 7;
            *(uint4*)&Bs[row][grp * 8] = *(const uint4*)&Bt[(long)(n0 + row) * K + k0 + grp * 8];
        }
        __syncthreads();
        #pragma unroll
        for (int kk = 0; kk < 2; kk++) {
            short8 a0 = *(const short8*)&As[mbase + l15][kk * 32 + ko * 8];
            short8 a1 = *(const short8*)&As[mbase + 16 + l15][kk * 32 + ko * 8];
            short8 bb[4];
            #pragma unroll
            for (int nt = 0; nt < 4; nt++)
                bb[nt] = *(const short8*)&Bs[nt * 16 + l15][kk * 32 + ko * 8];
            #pragma unroll
            for (int nt = 0; nt < 4; nt++) {
                acc[0][nt] = __builtin_amdgcn_mfma_f32_16x16x32_bf16(a0, bb[nt], acc[0][nt], 0, 0, 0);
                acc[1][nt] = __builtin_amdgcn_mfma_f32_16x16x32_bf16(a1, bb[nt], acc[1][nt], 0, 0, 0);
            }
        }
        __syncthreads();
    }
    #pragma unroll
    for (int nt = 0; nt < 4; nt++) {
        int n = n0 + nt * 16 + l15;
        if (n < N) {
            #pragma unroll
            for (int mt = 0; mt < 2; mt++)
                #pragma unroll
                for (int reg = 0; reg < 4; reg++) {
                    int m = m0 + mbase + mt * 16 + ko * 4 + reg;
                    C[(long)m * N + n] = acc[mt][nt][reg];
                }
        }
    }
}

// ---------------- conv3x3 512->512 via MFMA + gelu + bn, bf16 out, all dirs ----------------
// FROZEN at round-11 form (best measured: 308us, VGPR 64, Occ 46%). Do not touch.
__global__ __launch_bounds__(256, 2) void conv_mfma(
    const ushort* __restrict__ cinb, const ushort* __restrict__ wbf,
    const float* __restrict__ bn_g, const float* __restrict__ bn_b,
    const float* __restrict__ bn_m, const float* __restrict__ bn_v,
    ushort* __restrict__ convb)
{
    __shared__ ushort in_s[6][4][66][8];   // rows h0-1..h0+4, ko(4x8ci), px -1..64

    // XCD swizzle: slice = (d, co-tile) weight group; 4 slices per XCD
    int fid = blockIdx.x;
    int xcd = fid & 7;
    int k = fid >> 3;
    int slice = xcd * 4 + (k >> 5);
    int within = k & 31;
    int d = slice >> 3;
    int co0 = (slice & 7) * 64;
    int h0 = (within & 15) * 4;
    int b = within >> 4;
    int z = d * 2 + b;

    int t = threadIdx.x;
    int wave = t >> 6, lane = t & 63;
    int l15 = lane & 15, ko = lane >> 4;

    const ushort* conv_in = cinb + (long)z * LLEN * 512;
    ushort* conv_out = convb + (long)z * LLEN * 512;

    f32x4 acc[4][4];
    #pragma unroll
    for (int m = 0; m < 4; m++)
        #pragma unroll
        for (int nt = 0; nt < 4; nt++) acc[m][nt] = (f32x4){0.f, 0.f, 0.f, 0.f};

    // per-thread weight base: [d][tap][co0 + nt*16 + l15][ci0 + ko*8]
    const ushort* wtb = wbf + (long)d * 9 * 512 * 512 + (long)(co0 + l15) * 512 + ko * 8;

    for (int ci0 = 0; ci0 < 512; ci0 += 32) {
        // stage input: 6 rows x 66 px x 4 octs = 1584 x 16B (shift-only decode)
        for (int q = t; q < 1584; q += 256) {
            int oct = q & 3, pxg = q >> 2;
            int row = pxg / 66, px = pxg - row * 66;
            int hh = h0 + row - 1, wp = px - 1;
            uint4 val = make_uint4(0u, 0u, 0u, 0u);
            if (hh >= 0 && hh < 64 && wp >= 0 && wp < 64)
                val = *(const uint4*)&conv_in[(((long)hh) * 64 + wp) * 512 + ci0 + oct * 8];
            *(uint4*)&in_s[row][oct][px][0] = val;
        }
        // prefetch tap-0 weights
        const ushort* wp0 = wtb + ci0;
        short8 bw[4], bwn[4];
        #pragma unroll
        for (int nt = 0; nt < 4; nt++)
            bw[nt] = *(const short8*)&wp0[(long)nt * (16 * 512)];
        __syncthreads();
        #pragma unroll 1
        for (int tap = 0; tap < 9; tap++) {
            if (tap < 8) {
                const ushort* wq = wp0 + (long)(tap + 1) * (512 * 512);
                #pragma unroll
                for (int nt = 0; nt < 4; nt++)
                    bwn[nt] = *(const short8*)&wq[(long)nt * (16 * 512)];
            }
            int kh = (tap >= 6) ? 2 : ((tap >= 3) ? 1 : 0);
            int kw = tap - kh * 3;
            short8 av[4];
            #pragma unroll
            for (int m = 0; m < 4; m++)
                av[m] = *(const short8*)&in_s[wave + kh][ko][m * 16 + l15 + kw][0];
            #pragma unroll
            for (int m = 0; m < 4; m++)
                #pragma unroll
                for (int nt = 0; nt < 4; nt++)
                    acc[m][nt] = __builtin_amdgcn_mfma_f32_16x16x32_bf16(av[m], bw[nt], acc[m][nt], 0, 0, 0);
            #pragma unroll
            for (int nt = 0; nt < 4; nt++) bw[nt] = bwn[nt];
        }
        __syncthreads();
    }

    // epilogue: gelu(tanh approx via fast exp) + BN, write bf16 (B,L,512)
    int hgl = h0 + wave;
    #pragma unroll
    for (int nt = 0; nt < 4; nt++) {
        int co = co0 + nt * 16 + l15;
        float mean = bn_m[d * 512 + co], var = bn_v[d * 512 + co];
        float g = bn_g[d * 512 + co], bbias = bn_b[d * 512 + co];
        float inv = rsqrtf(var + 1e-3f);
        #pragma unroll
        for (int m = 0; m < 4; m++)
            #pragma unroll
            for (int reg = 0; reg < 4; reg++) {
                int wc = m * 16 + ko * 4 + reg;
                float v = acc[m][nt][reg];
                float u = -1.5957691216057308f * (v + 0.044715f * v * v * v);
                v = v / (1.f + __expf(u));
                v = (v - mean) * inv * g + bbias;
                conv_out[((long)hgl * 64 + wc) * 512 + co] = f2bf(v);
            }
    }
}

// ---------------- scan phase 1: per-chunk (Aprod, hfin), all 4 dirs ----------------
// 128 chunks x 32 steps: 1024 blocks (4/CU) — measured best tradeoff (r16: 420us;
// 256x16 regressed via quadratic prefix-fold work, r17).
__global__ __launch_bounds__(256) void scan_chunk(
    const float* __restrict__ bcdt, const ushort* __restrict__ conv_out,
    const int* __restrict__ mortonH, const int* __restrict__ mortonV,
    const float* __restrict__ fcos, const float* __restrict__ fsin,
    const float* __restrict__ dt_bias, const float* __restrict__ A_log,
    float* __restrict__ hfin, float* __restrict__ aprod_out)
{
    int chunk = blockIdx.x, b = blockIdx.y, d = blockIdx.z;
    const int* idx = (d < 2) ? mortonH : mortonV;
    int flip = d & 1;
    int c = threadIdx.x;
    int hh = c >> 5, p = c & 31;
    int i = p >> 1;
    float Acoef = -__expf(A_log[d * 8 + hh]);
    float dtb = dt_bias[d * 8 + hh];
    float hstate = 0.f, aprod = 1.f;
    const ushort* cop = conv_out + (long)(d * BATCH + b) * LLEN * 512;
    for (int jj = 0; jj < CLEN; jj++) {
        int j = chunk * CLEN + jj;
        int jsrc = flip ? (LLEN - 1 - j) : j;
        int src = idx[jsrc];
        const float* bc = bcdt + ((long)b * LLEN + src) * 48 + d * 12;
        float dtraw = bc[2 + hh] + dtb;
        float dtv = (dtraw > 20.f) ? dtraw : __logf(1.f + __expf(dtraw));
        float a = __expf(dtv * Acoef);
        float Bd = bc[0];
        const ushort* xrow = cop + (long)src * 512;
        uint xz = *(const uint*)&xrow[hh * 32 + (p & ~1)];
        float xe = bf2f((ushort)(xz & 0xffff));
        float xo = bf2f((ushort)(xz >> 16));
        float cs = fcos[j * 16 + i], sn = fsin[j * 16 + i];
        float xh = (p & 1) ? (xe * sn + xo * cs) : (xe * cs - xo * sn);
        hstate = a * hstate + dtv * xh * Bd;
        aprod *= a;
    }
    long o = (((long)(d * BATCH + b)) * NCHUNK + chunk) * 256 + c;
    hfin[o] = hstate;
    aprod_out[o] = aprod;
}

// ---------------- scan phase 2+3 fused: prefix fold + recompute + y + scatter ----------------
__global__ __launch_bounds__(256) void scan_final(
    const float* __restrict__ bcdt, const ushort* __restrict__ conv_out,
    const int* __restrict__ mortonH, const int* __restrict__ mortonV,
    const float* __restrict__ fcos, const float* __restrict__ fsin,
    const float* __restrict__ dt_bias, const float* __restrict__ A_log, const float* __restrict__ Dp,
    const float* __restrict__ hfin, const float* __restrict__ aprod, ushort* __restrict__ ycat)
{
    int chunk = blockIdx.x, b = blockIdx.y, d = blockIdx.z;
    const int* idx = (d < 2) ? mortonH : mortonV;
    int flip = d & 1;
    int c = threadIdx.x;
    int hh = c >> 5, p = c & 31;
    int i = p >> 1;
    float Acoef = -__expf(A_log[d * 8 + hh]);
    float dtb = dt_bias[d * 8 + hh];
    float Dv = Dp[d * 8 + hh];
    // prefix fold over preceding chunks
    float hstate = 0.f;
    {
        long ob = ((long)(d * BATCH + b)) * NCHUNK;
        for (int ch = 0; ch < chunk; ch++) {
            long o = (ob + ch) * 256 + c;
            hstate = aprod[o] * hstate + hfin[o];
        }
    }
    const ushort* cop = conv_out + (long)(d * BATCH + b) * LLEN * 512;
    for (int jj = 0; jj < CLEN; jj++) {
        int j = chunk * CLEN + jj;
        int jsrc = flip ? (LLEN - 1 - j) : j;
        int src = idx[jsrc];
        const float* bc = bcdt + ((long)b * LLEN + src) * 48 + d * 12;
        float dtraw = bc[2 + hh] + dtb;
        float dtv = (dtraw > 20.f) ? dtraw : __logf(1.f + __expf(dtraw));
        float a = __expf(dtv * Acoef);
        float Bd = bc[0];
        float Cd = bc[1];
        const ushort* xrow = cop + (long)src * 512;
        uint xz = *(const uint*)&xrow[hh * 32 + (p & ~1)];
        float xe = bf2f((ushort)(xz & 0xffff));
        float xo = bf2f((ushort)(xz >> 16));
        float cs = fcos[j * 16 + i], sn = fsin[j * 16 + i];
        float xh = (p & 1) ? (xe * sn + xo * cs) : (xe * cs - xo * sn);
        hstate = a * hstate + dtv * xh * Bd;
        float y = hstate * Cd + Dv * xh;
        float zd = bf2f(xrow[256 + c]);
        y *= zd / (1.f + __expf(-zd));         // y * silu(zd)
        ycat[((long)b * LLEN + src) * 1024 + d * 256 + c] = f2bf(y);
    }
}

// ---------------- layernorm + transpose to (B,C,H,W) ----------------
__global__ __launch_bounds__(256) void ln_out(
    const float* __restrict__ pre, const float* __restrict__ g, const float* __restrict__ bta,
    float* __restrict__ out)
{
    int row = blockIdx.x;  // b*L + l
    int c = threadIdx.x;
    float v = pre[(long)row * 256 + c];
    float s = v, s2 = v * v;
    #pragma unroll
    for (int o = 32; o > 0; o >>= 1) {
        s += __shfl_down(s, o);
        s2 += __shfl_down(s2, o);
    }
    __shared__ float ss[4], ss2[4];
    __shared__ float mean_s, inv_s;
    int wid = c >> 6;
    if ((c & 63) == 0) { ss[wid] = s; ss2[wid] = s2; }
    __syncthreads();
    if (c == 0) {
        float S = ss[0] + ss[1] + ss[2] + ss[3];
        float S2 = ss2[0] + ss2[1] + ss2[2] + ss2[3];
        float mean = S / 256.f;
        float var = S2 / 256.f - mean * mean;
        mean_s = mean;
        inv_s = rsqrtf(var + 1e-6f);
    }
    __syncthreads();
    float o = (v - mean_s) * inv_s * g[c] + bta[c];
    int b = row >> 12, l = row & (LLEN - 1);
    out[((long)b * 256 + c) * (long)LLEN + l] = o;
}

extern "C" void kernel_launch(void* const* d_in, const int* in_sizes, int n_in,
                              void* d_out, int out_size, void* d_ws, size_t ws_size,
                              hipStream_t stream)
{
    const float* x        = (const float*)d_in[0];
    const float* fcos     = (const float*)d_in[1];
    const float* fsin     = (const float*)d_in[2];
    const int*   mortonH  = (const int*)d_in[3];
    const int*   mortonV  = (const int*)d_in[4];
    const float* W_in     = (const float*)d_in[7];
    const float* conv_w   = (const float*)d_in[8];
    const float* bn_g     = (const float*)d_in[9];
    const float* bn_b     = (const float*)d_in[10];
    const float* bn_m     = (const float*)d_in[11];
    const float* bn_v     = (const float*)d_in[12];
    const float* dt_bias  = (const float*)d_in[13];
    const float* A_log    = (const float*)d_in[14];
    const float* Dp       = (const float*)d_in[15];
    const float* W_out    = (const float*)d_in[16];
    const float* ln_g     = (const float*)d_in[17];
    const float* ln_b     = (const float*)d_in[18];
    float* out = (float*)d_out;

    float* ws = (float*)d_ws;
    // float-unit offsets
    const long CONVB_OFF   = 0;                                          // bf16 [4][2][4096][512] -> 8388608 slots
    const long HFIN_OFF    = CONVB_OFF + 8388608;                        // [4][2][128][256] f32
    const long APROD_OFF   = HFIN_OFF + 4L * BATCH * NCHUNK * 256;
    const long BCDT_OFF    = APROD_OFF + 4L * BATCH * NCHUNK * 256;      // (2*4096,48) f32
    const long WBF_OFF     = BCDT_OFF + (long)BATCH * LLEN * 48;         // bf16 4*9*512*512 -> 4718592 slots
    const long CINB_OFF    = WBF_OFF + 4718592;                          // bf16 4*2*4096*512 -> 8388608 slots
    const long XBF_OFF     = CINB_OFF + 8388608;                         // bf16 2*4096*256 -> 1048576 slots
    const long WINT_OFF    = XBF_OFF + 1048576;                          // bf16 2112*256 -> 270336 slots
    const long WOUTT_OFF   = WINT_OFF + 270336;                          // bf16 256*1024 -> 131072 slots
    const long YCATB_OFF   = WOUTT_OFF + 131072;                         // bf16 2*4096*1024 -> 4194304 slots
    const long PRE_OFF     = YCATB_OFF + 4194304;                        // (2,4096,256) f32

    ushort* convb   = (ushort*)(ws + CONVB_OFF);
    float* hfin     = ws + HFIN_OFF;
    float* aprod    = ws + APROD_OFF;
    float* bcdt     = ws + BCDT_OFF;
    ushort* wbf     = (ushort*)(ws + WBF_OFF);
    ushort* cinb    = (ushort*)(ws + CINB_OFF);
    ushort* xbf     = (ushort*)(ws + XBF_OFF);
    ushort* wint    = (ushort*)(ws + WINT_OFF);
    ushort* woutt   = (ushort*)(ws + WOUTT_OFF);
    ushort* ycatb   = (ushort*)(ws + YCATB_OFF);
    float* pre      = ws + PRE_OFF;

    // 0) one-time converts
    convert_w<<<4 * 512, 256, 0, stream>>>(conv_w, wbf);
    convert_wt<<<dim3(NPROJ_PAD / 32, CDIM / 32), 256, 0, stream>>>(W_in, wint, CDIM, NPROJ);
    convert_wt<<<dim3(CDIM / 32, 1024 / 32), 256, 0, stream>>>(W_out, woutt, 1024, CDIM);
    convert_x<<<dim3(LLEN / 32, CDIM / 32, BATCH), 256, 0, stream>>>(x, xbf);

    // 1) in-proj GEMM fused with direction scatter: M=8192, N=2088(pad 2112), K=256
    gemm_in<<<dim3(64, NPROJ_PAD / 64), 256, 0, stream>>>(xbf, wint, cinb, bcdt);

    // 2) conv (all directions, one dispatch): 1-D grid 1024 with XCD swizzle
    conv_mfma<<<1024, 256, 0, stream>>>(
        cinb, wbf, bn_g, bn_b, bn_m, bn_v, convb);

    // 3) scans (all directions merged; 128 chunks x 32 steps)
    scan_chunk<<<dim3(NCHUNK, BATCH, 4), 256, 0, stream>>>(
        bcdt, convb, mortonH, mortonV, fcos, fsin, dt_bias, A_log, hfin, aprod);
    scan_final<<<dim3(NCHUNK, BATCH, 4), 256, 0, stream>>>(
        bcdt, convb, mortonH, mortonV, fcos, fsin, dt_bias, A_log, Dp, hfin, aprod, ycatb);

    // 4) out GEMM: M=8192, N=256, K=1024
    gemm_bt<<<dim3(64, CDIM / 64), 256, 0, stream>>>(ycatb, woutt, pre, 1024, CDIM);

    // 5) LN + transpose
    ln_out<<<BATCH * LLEN, 256, 0, stream>>>(pre, ln_g, ln_b, out);
}